// Round 9
// baseline (293.652 us; speedup 1.0000x reference)
//
#include <hip/hip_runtime.h>
#include <hip/hip_bf16.h>
#include <stdint.h>

#define Bn 4
#define Cn 64
#define Fn 50000
#define Kn 16
#define NTOT (Bn*Fn)
#define EPS 1e-5f

typedef unsigned short u16;
typedef unsigned int u32;
typedef __attribute__((ext_vector_type(8))) short short8;
typedef __attribute__((ext_vector_type(4))) float f32x4;

__device__ __forceinline__ u16 f2bf(float x) {
  __hip_bfloat16 h = __float2bfloat16(x);
  return *reinterpret_cast<u16*>(&h);
}
__device__ __forceinline__ u32 pack2(float a, float b) {
  return (u32)f2bf(a) | ((u32)f2bf(b) << 16);
}

// K1 (MFMA): unchanged from R8 (control). Gt[(b*4+seg)][f][16ch] bf16.
__global__ __launch_bounds__(256) void k1_mfma(
    const float* __restrict__ fea, const float* __restrict__ W,
    u32* __restrict__ Gt) {
  const int b = blockIdx.y;
  const int f0 = blockIdx.x * 128;
  const int t = threadIdx.x;
  const int l = t & 63;
  const int quad = l >> 4;
  const int lane15 = l & 15;
  const int wv = t >> 6;
  __shared__ float a_s[64][129];   // 33 KB -> 4 blocks/CU

  short8 afr[4][2];
  #pragma unroll
  for (int ot = 0; ot < 4; ot++) {
    #pragma unroll
    for (int kk = 0; kk < 2; kk++) {
      const float* wr = W + (ot * 16 + lane15) * 64 + kk * 32 + quad * 8;
      float4 wa = *(const float4*)wr;
      float4 wb = *(const float4*)(wr + 4);
      union { short8 v; u32 u[4]; } fr;
      fr.u[0] = pack2(wa.x, wa.y); fr.u[1] = pack2(wa.z, wa.w);
      fr.u[2] = pack2(wb.x, wb.y); fr.u[3] = pack2(wb.z, wb.w);
      afr[ot][kk] = fr.v;
    }
  }

  {
    const float* fb = fea + (size_t)b * Cn * Fn;
    const int f4 = t & 31;
    const int cbase = t >> 5;
    const bool fvalid = (f0 + f4 * 4) < Fn;
    #pragma unroll
    for (int jj = 0; jj < 8; jj++) {
      int c = cbase + jj * 8;
      float4 v = make_float4(0.f, 0.f, 0.f, 0.f);
      if (fvalid) v = *(const float4*)(fb + (size_t)c * Fn + f0 + f4 * 4);
      *(float4*)&a_s[c][f4 * 4] = v;
    }
  }
  __syncthreads();

  f32x4 acc[4][2];
  #pragma unroll
  for (int ot = 0; ot < 4; ot++)
    #pragma unroll
    for (int ft = 0; ft < 2; ft++) acc[ot][ft] = (f32x4){0.f, 0.f, 0.f, 0.f};

  #pragma unroll
  for (int ft = 0; ft < 2; ft++) {
    const int fl = wv * 32 + ft * 16 + lane15;
    float x[16];
    #pragma unroll
    for (int j = 0; j < 8; j++) x[j] = a_s[quad * 8 + j][fl];
    #pragma unroll
    for (int j = 0; j < 8; j++) x[8 + j] = a_s[32 + quad * 8 + j][fl];
    union { short8 s; u32 u[4]; } b0, b1;
    #pragma unroll
    for (int p = 0; p < 4; p++) {
      b0.u[p] = pack2(x[2 * p], x[2 * p + 1]);
      b1.u[p] = pack2(x[8 + 2 * p], x[8 + 2 * p + 1]);
    }
    #pragma unroll
    for (int ot = 0; ot < 4; ot++) {
      acc[ot][ft] = __builtin_amdgcn_mfma_f32_16x16x32_bf16(afr[ot][0], b0.s, acc[ot][ft], 0, 0, 0);
      acc[ot][ft] = __builtin_amdgcn_mfma_f32_16x16x32_bf16(afr[ot][1], b1.s, acc[ot][ft], 0, 0, 0);
    }
  }

  #pragma unroll
  for (int ot = 0; ot < 4; ot++) {
    #pragma unroll
    for (int ft = 0; ft < 2; ft++) {
      int fg = f0 + wv * 32 + ft * 16 + lane15;
      if (fg < Fn) {
        uint2 pv;
        pv.x = pack2(acc[ot][ft][0], acc[ot][ft][1]);
        pv.y = pack2(acc[ot][ft][2], acc[ot][ft][3]);
        *(uint2*)(Gt + ((size_t)(b * 4 + ot) * Fn + fg) * 8 + quad * 2) = pv;
      }
    }
  }
}

// K2 (single-wave blocks): block = one wave = (b,seg) combo x 32 faces.
// Same 32 B-row / 2-lanes-per-row gather; barrier is intra-wave (free),
// so up to 8 independent waves/SIMD stream gathers concurrently.
__global__ __launch_bounds__(64) void k2_gather_w(
    const u32* __restrict__ Gt, const int* __restrict__ ring,
    const float* __restrict__ bias, u32* __restrict__ Y,
    float* __restrict__ gsum, float* __restrict__ gsum2) {
  const int bid = blockIdx.x;
  const int combo = bid & 15;         // XCD affinity via bid%8
  const int ft = bid >> 4;            // 32-face tile
  const int b = combo >> 2;
  const int seg = combo & 3;
  const int t = threadIdx.x;          // 0..63
  const int face_l = t >> 1;          // 0..31
  const int half = t & 1;
  const int fa = ft * 32 + face_l;
  const bool valid = fa < Fn;

  __shared__ float y_s[32][17];
  __shared__ float rs[2][16];
  __shared__ float rs2[2][16];

  float acc[8];
  #pragma unroll
  for (int i = 0; i < 8; i++) acc[i] = 0.f;

  const int c0 = seg * 16 + half * 8;
  float bv[8];
  #pragma unroll
  for (int i = 0; i < 8; i++) bv[i] = bias[c0 + i];

  if (valid) {
    const int4* rp = (const int4*)(ring + ((size_t)b * Fn + fa) * Kn);
    int4 i0 = rp[0], i1 = rp[1], i2 = rp[2], i3 = rp[3];
    int idx[16] = {i0.x,i0.y,i0.z,i0.w, i1.x,i1.y,i1.z,i1.w,
                   i2.x,i2.y,i2.z,i2.w, i3.x,i3.y,i3.z,i3.w};
    const uint4* Gs = (const uint4*)(Gt + (size_t)combo * Fn * 8);
    uint4 v[8], w[8];
    #pragma unroll
    for (int k = 0; k < 8; k++) v[k] = Gs[(size_t)idx[k] * 2 + half];
    #pragma unroll
    for (int k = 0; k < 8; k++) w[k] = Gs[(size_t)idx[8 + k] * 2 + half];
    #pragma unroll
    for (int k = 0; k < 8; k++) {
      u32 uu[4] = {v[k].x, v[k].y, v[k].z, v[k].w};
      #pragma unroll
      for (int p = 0; p < 4; p++) {
        acc[2*p]   += __uint_as_float(uu[p] << 16);
        acc[2*p+1] += __uint_as_float(uu[p] & 0xffff0000u);
      }
    }
    #pragma unroll
    for (int k = 0; k < 8; k++) {
      u32 uu[4] = {w[k].x, w[k].y, w[k].z, w[k].w};
      #pragma unroll
      for (int p = 0; p < 4; p++) {
        acc[2*p]   += __uint_as_float(uu[p] << 16);
        acc[2*p+1] += __uint_as_float(uu[p] & 0xffff0000u);
      }
    }
  }
  #pragma unroll
  for (int i = 0; i < 8; i++) acc[i] = valid ? acc[i] + bv[i] : 0.f;
  #pragma unroll
  for (int i = 0; i < 8; i++) y_s[face_l][half * 8 + i] = acc[i];
  __syncthreads();   // single wave: compiles to lgkmcnt wait, no real barrier

  {  // Y write: 16 ch x 16 u32 = 256 u32; 4 per thread
    const int fp = t & 15, cgrp = t >> 4;    // face-pair, ch group
    const int fa2 = ft * 16 + fp;
    if (fa2 < Fn / 2) {
      #pragma unroll
      for (int j = 0; j < 4; j++) {
        int ch = cgrp * 4 + j;
        Y[((size_t)b * 64 + seg * 16 + ch) * (Fn / 2) + fa2] =
            pack2(y_s[fp * 2][ch], y_s[fp * 2 + 1][ch]);
      }
    }
  }
  {  // stats: 2 parts x 16 channels over 32 faces
    const int ch = t & 15, part = (t >> 4) & 1;
    if (t < 32) {
      float s = 0.f, s2 = 0.f;
      #pragma unroll
      for (int i = 0; i < 16; i++) {
        float v = y_s[part * 16 + i][ch];
        s += v; s2 += v * v;
      }
      rs[part][ch] = s; rs2[part][ch] = s2;
    }
  }
  __syncthreads();
  if (t < 16) {
    atomicAdd(&gsum[seg * 16 + t], rs[0][t] + rs[1][t]);
  } else if (t < 32) {
    const int ch = t - 16;
    atomicAdd(&gsum2[seg * 16 + ch], rs2[0][ch] + rs2[1][ch]);
  }
}

// k4 (bf16, stats fused): unchanged from R8 (control).
__global__ __launch_bounds__(256) void k4_norm_bf(
    const u32* __restrict__ Y, const float* __restrict__ gsum,
    const float* __restrict__ gsum2, const float* __restrict__ gamma,
    const float* __restrict__ beta, float* __restrict__ out) {
  int i = blockIdx.x * 256 + threadIdx.x;   // uint2 index; exact cover
  int ch = (i / 12500) & 63;
  const float inv = 1.0f / (float)NTOT;
  float mean = gsum[ch] * inv;
  float var = gsum2[ch] * inv - mean * mean;
  float a = gamma[ch] * rsqrtf(var + EPS);
  float cc = beta[ch] - mean * a;
  uint2 u = ((const uint2*)Y)[i];
  float4 v;
  v.x = fmaxf(fmaf(__uint_as_float(u.x << 16), a, cc), 0.f);
  v.y = fmaxf(fmaf(__uint_as_float(u.x & 0xffff0000u), a, cc), 0.f);
  v.z = fmaxf(fmaf(__uint_as_float(u.y << 16), a, cc), 0.f);
  v.w = fmaxf(fmaf(__uint_as_float(u.y & 0xffff0000u), a, cc), 0.f);
  ((float4*)out)[i] = v;
}

extern "C" void kernel_launch(void* const* d_in, const int* in_sizes, int n_in,
                              void* d_out, int out_size, void* d_ws, size_t ws_size,
                              hipStream_t stream) {
  const float* fea   = (const float*)d_in[0];
  const int*   ring  = (const int*)d_in[1];
  const float* W     = (const float*)d_in[2];
  const float* bias  = (const float*)d_in[3];
  const float* gamma = (const float*)d_in[4];
  const float* beta  = (const float*)d_in[5];
  float* out = (float*)d_out;

  u32* Gt = (u32*)d_ws;                                   // [B*4][Fn][8 u32] = 25.6 MB
  const size_t gtBytes = (size_t)Bn * 4 * Fn * 8 * 4;
  u32* Y = (u32*)((char*)d_ws + gtBytes);                 // 25.6 MB
  const size_t yBytes  = (size_t)Bn * 64 * (Fn / 2) * 4;
  float* gsum  = (float*)((char*)d_ws + gtBytes + yBytes);
  float* gsum2 = gsum + 64;

  hipMemsetAsync(gsum, 0, 2 * 64 * sizeof(float), stream);
  k1_mfma<<<dim3((Fn + 127) / 128, Bn), 256, 0, stream>>>(fea, W, Gt);
  const int ftiles = (Fn + 31) / 32;                      // 1563
  k2_gather_w<<<dim3(ftiles * 16), 64, 0, stream>>>(Gt, ring, bias, Y, gsum, gsum2);
  k4_norm_bf<<<dim3(Bn * 64 * 12500 / 256), 256, 0, stream>>>(Y, gsum, gsum2, gamma, beta, out);
}